// Round 13
// baseline (388.992 us; speedup 1.0000x reference)
//
#include <hip/hip_runtime.h>
#include <hip/hip_bf16.h>
#include <stdint.h>

#define B_ 16
#define N_ 64
#define S_ 4096
#define C_ 384
#define H_ 6
#define DH_ 64
#define SCALE_ 0.125f
#define TAU_ 2e-4f
#define LISTCAP 262144

typedef __attribute__((ext_vector_type(8))) short bf16x8;
typedef __attribute__((ext_vector_type(4))) float f32x4;
typedef __attribute__((ext_vector_type(4))) unsigned short u16x4;

static __device__ __forceinline__ unsigned short f2bf(float x) {
    union { float f; unsigned u; } v; v.f = x;
    unsigned r = v.u + 0x7FFFu + ((v.u >> 16) & 1u);
    return (unsigned short)(r >> 16);
}
static __device__ __forceinline__ float bf2f(unsigned short b) {
    union { unsigned u; float f; } v; v.u = ((unsigned)b) << 16; return v.f;
}

// async global->LDS, 16B/lane; LDS dest = wave-uniform base + lane*16
static __device__ __forceinline__ void gl_lds16(const void* g, void* l) {
    __builtin_amdgcn_global_load_lds(
        (const __attribute__((address_space(1))) unsigned int*)g,
        (__attribute__((address_space(3))) unsigned int*)l, 16, 0, 0);
}

// ---------------------------------------------------------------------------
// K0+K1 fused: prep (key->khi/klo, coalesced) + qk (LDS-staged Wq) + Wp/Wv
// transpose tiles. ROUND-THIS (revert-recombine): r11/r12's fp32-key attn
// staging produced 4.7M bank conflicts INDEPENDENT of read encoding (typed
// b128 vs char*-XOR: identical counts) — the 128B-row-stride layout itself
// conflicts where the 64B-row bf16 layout measured 0. Pre-committed revert:
// prep restored (bf16 hi/lo), attn back to the known-0-conflict r10 kernel.
// Kept from r11/r12: aggv on raw fp32 key (absmax 0.00195), hist@1024,
// WpT/WvT, LDS-staged Wq.
// ---------------------------------------------------------------------------
#define PREP_BLOCKS 8192   // 8192 * 3072 elems = 16*4096*384
#define QK_BLOCKS   (8 * H_ * B_)   // 768
#define TR_BLOCKS   72              // 2 matrices x 36 (64x64) tiles

#define TRT(r, c) sbuf[(r) * 65 + (c)]
#define WQS(d, c) sbuf[(d) * 49 + (c)]

__global__ __launch_bounds__(384) void prepqk_kernel(const float* __restrict__ key,
                                                     unsigned short* __restrict__ khi,
                                                     unsigned short* __restrict__ klo,
                                                     const float* __restrict__ query,
                                                     const float* __restrict__ Wq,
                                                     const float* __restrict__ Wk,
                                                     float* __restrict__ qk,
                                                     unsigned short* __restrict__ qkhi,
                                                     unsigned short* __restrict__ qklo,
                                                     const float* __restrict__ Wp,
                                                     const float* __restrict__ Wv,
                                                     float* __restrict__ wpT,
                                                     float* __restrict__ wvT) {
    __shared__ float qstage[8][C_];
    __shared__ float qv[8][DH_];
    __shared__ float sbuf[64 * 65];
    int t = threadIdx.x;
    if (blockIdx.x < PREP_BLOCKS) {
        size_t blk = (size_t)blockIdx.x * 3072;
#pragma unroll
        for (int half = 0; half < 2; ++half) {
            size_t base = blk + (size_t)half * 1536 + (size_t)t * 4;
            float4 x = *(const float4*)(key + base);
            float xs[4] = { x.x, x.y, x.z, x.w };
            unsigned short hi[4], lo[4];
#pragma unroll
            for (int i = 0; i < 4; ++i) {
                hi[i] = f2bf(xs[i]);
                lo[i] = f2bf(xs[i] - bf2f(hi[i]));
            }
            *(u16x4*)(khi + base) = *(u16x4*)hi;
            *(u16x4*)(klo + base) = *(u16x4*)lo;
        }
        return;
    }
    int e = blockIdx.x - PREP_BLOCKS;
    if (e >= QK_BLOCKS) {
        // ---- transpose part: WpT[c][j] = Wp[j][c], WvT likewise ----
        int e2 = e - QK_BLOCKS;                 // 0..71
        const float* src = (e2 < 36) ? Wp : Wv;
        float* dst = (e2 < 36) ? wpT : wvT;
        int tile = e2 % 36;
        int r0 = (tile / 6) * 64, c0 = (tile % 6) * 64;
        if (t < 256) {
#pragma unroll
            for (int rep = 0; rep < 16; ++rep) {
                int idx = rep * 256 + t;
                int r = idx >> 6, c = idx & 63;
                TRT(r, c) = src[(size_t)(r0 + r) * C_ + c0 + c];
            }
        }
        __syncthreads();
        if (t < 256) {
#pragma unroll
            for (int rep = 0; rep < 16; ++rep) {
                int idx = rep * 256 + t;
                int rT = idx >> 6, cT = idx & 63;
                dst[(size_t)(c0 + rT) * C_ + r0 + cT] = TRT(cT, rT);
            }
        }
        return;
    }
    // ---- qk part (LDS-staged Wq, r10 logic — qv/qk/qkhi/qklo bit-identical) ----
    int ng = e & 7;
    int h = (e >> 3) % H_;
    int b = e / (8 * H_);
    int n0 = ng * 8;
#pragma unroll
    for (int i = 0; i < 8; ++i)
        qstage[i][t] = query[((size_t)(b * N_ + n0 + i)) * C_ + t];
    {
        int i0 = (t < 256) ? (t >> 6) : 0;
        int d = t & 63;
        float accA = 0.f, accB = 0.f;
        for (int c0 = 0; c0 < C_; c0 += 48) {
            __syncthreads();
#pragma unroll
            for (int rep = 0; rep < 8; ++rep) {
                int idx2 = rep * 384 + t;
                int r = idx2 / 48, c = idx2 % 48;
                WQS(r, c) = Wq[(size_t)(h * DH_ + r) * C_ + c0 + c];
            }
            __syncthreads();
            if (t < 256) {
#pragma unroll
                for (int cc = 0; cc < 48; cc += 4) {
                    accA += qstage[i0][c0 + cc + 0] * WQS(d, cc + 0)
                          + qstage[i0][c0 + cc + 1] * WQS(d, cc + 1)
                          + qstage[i0][c0 + cc + 2] * WQS(d, cc + 2)
                          + qstage[i0][c0 + cc + 3] * WQS(d, cc + 3);
                    accB += qstage[i0 + 4][c0 + cc + 0] * WQS(d, cc + 0)
                          + qstage[i0 + 4][c0 + cc + 1] * WQS(d, cc + 1)
                          + qstage[i0 + 4][c0 + cc + 2] * WQS(d, cc + 2)
                          + qstage[i0 + 4][c0 + cc + 3] * WQS(d, cc + 3);
                }
            }
        }
        if (t < 256) {
            qv[i0][d] = accA * SCALE_;
            qv[i0 + 4][d] = accB * SCALE_;
        }
    }
    __syncthreads();
    float a[8];
#pragma unroll
    for (int i = 0; i < 8; ++i) a[i] = 0.f;
    {
        const float* wk = Wk + (size_t)h * DH_ * C_ + t;
#pragma unroll 4
        for (int d = 0; d < DH_; ++d) {
            float w = wk[(size_t)d * C_];
#pragma unroll
            for (int i = 0; i < 8; ++i) a[i] += qv[i][d] * w;
        }
    }
#pragma unroll
    for (int i = 0; i < 8; ++i) qstage[i][t] = a[i];
    __syncthreads();
    {
        int r = t / 48, c0 = (t % 48) * 8;
        float v[8];
#pragma unroll
        for (int j = 0; j < 8; ++j) v[j] = qstage[r][c0 + j];
        unsigned short hi[8], lo[8];
#pragma unroll
        for (int j = 0; j < 8; ++j) {
            hi[j] = f2bf(v[j]);
            lo[j] = f2bf(v[j] - bf2f(hi[j]));
        }
        size_t o = ((size_t)(b * H_ + h) * N_ + n0 + r) * C_ + c0;
        float4 f0 = { v[0], v[1], v[2], v[3] };
        float4 f1 = { v[4], v[5], v[6], v[7] };
        *(float4*)(qk + o) = f0;
        *(float4*)(qk + o + 4) = f1;
        *(bf16x8*)(qkhi + o) = *(bf16x8*)hi;
        *(bf16x8*)(qklo + o) = *(bf16x8*)lo;
    }
}

// ---------------------------------------------------------------------------
// K2: attn — r10's bf16 MFMA kernel, byte-for-byte (known-good: 91us,
// 0 bank conflicts, MfmaUtil 27%). 64n x 128 tokens per block.
// ---------------------------------------------------------------------------
__global__ __launch_bounds__(256) void attn_kernel(const unsigned short* __restrict__ qkhi,
                                                   const unsigned short* __restrict__ qklo,
                                                   const unsigned short* __restrict__ khi,
                                                   const unsigned short* __restrict__ klo,
                                                   unsigned int* __restrict__ idx,
                                                   unsigned int* __restrict__ flag_cnt,
                                                   unsigned int* __restrict__ flag_list) {
    __shared__ __align__(16) unsigned short sAhi[64 * 32];
    __shared__ __align__(16) unsigned short sAlo[64 * 32];
    __shared__ __align__(16) unsigned short sBhi[128 * 32];
    __shared__ __align__(16) unsigned short sBlo[128 * 32];
    int tid = threadIdx.x;
    int w = tid >> 6, l = tid & 63;
    int wm = w >> 1, wn = w & 1;
    int q4 = l >> 4, lm = l & 15;
    int s0 = blockIdx.x * 128;
    int h = blockIdx.y, b = blockIdx.z;
    size_t kbK = ((size_t)b * S_ + s0) * C_;
    size_t kbA = (size_t)(b * H_ + h) * N_ * C_;
    int trow16 = l >> 2;
    int tquart = ((l & 3) ^ ((l >> 3) & 3)) * 8;
    int sw = (q4 ^ ((lm >> 1) & 3)) * 8;

    f32x4 acc[2][4];
#pragma unroll
    for (int tm = 0; tm < 2; ++tm)
#pragma unroll
        for (int nt = 0; nt < 4; ++nt) acc[tm][nt] = (f32x4)0.f;

    for (int kc = 0; kc < C_; kc += 32) {
        __syncthreads();
        // 24 granules (1KB each: 16 rows x 32 cols bf16): 8 Bhi, 8 Blo, 4 Ahi, 4 Alo
#pragma unroll
        for (int i = 0; i < 6; ++i) {
            int gid = w * 6 + i;
            if (gid < 8) {
                gl_lds16(khi + kbK + (size_t)(gid * 16 + trow16) * C_ + kc + tquart,
                         (char*)sBhi + gid * 1024);
            } else if (gid < 16) {
                int g2 = gid - 8;
                gl_lds16(klo + kbK + (size_t)(g2 * 16 + trow16) * C_ + kc + tquart,
                         (char*)sBlo + g2 * 1024);
            } else if (gid < 20) {
                int g2 = gid - 16;
                gl_lds16(qkhi + kbA + (size_t)(g2 * 16 + trow16) * C_ + kc + tquart,
                         (char*)sAhi + g2 * 1024);
            } else {
                int g2 = gid - 20;
                gl_lds16(qklo + kbA + (size_t)(g2 * 16 + trow16) * C_ + kc + tquart,
                         (char*)sAlo + g2 * 1024);
            }
        }
        __syncthreads();
        bf16x8 ah[2], al[2];
#pragma unroll
        for (int tm = 0; tm < 2; ++tm) {
            int ar = (wm * 32 + tm * 16 + lm) * 32 + sw;
            ah[tm] = *(const bf16x8*)&sAhi[ar];
            al[tm] = *(const bf16x8*)&sAlo[ar];
        }
#pragma unroll
        for (int nt = 0; nt < 4; ++nt) {
            int nr = ((wn * 4 + nt) * 16 + lm) * 32 + sw;
            bf16x8 bh = *(const bf16x8*)&sBhi[nr];
            bf16x8 bl = *(const bf16x8*)&sBlo[nr];
#pragma unroll
            for (int tm = 0; tm < 2; ++tm) {
                acc[tm][nt] = __builtin_amdgcn_mfma_f32_16x16x32_bf16(ah[tm], bh, acc[tm][nt], 0, 0, 0);
                acc[tm][nt] = __builtin_amdgcn_mfma_f32_16x16x32_bf16(ah[tm], bl, acc[tm][nt], 0, 0, 0);
                acc[tm][nt] = __builtin_amdgcn_mfma_f32_16x16x32_bf16(al[tm], bh, acc[tm][nt], 0, 0, 0);
            }
        }
    }
    __syncthreads();

    float* rm1 = (float*)sBhi;   // scratch aliases sBhi; safe after final barrier
    float* rm2 = rm1 + 256;
    int* ri1 = (int*)(rm2 + 256);
    int* ri2 = ri1 + 256;

#pragma unroll
    for (int nt = 0; nt < 4; ++nt) {
        float m1 = -3.4e38f, m2 = -3.4e38f; int i1 = 0, i2 = 0;
#pragma unroll
        for (int tm = 0; tm < 2; ++tm)
#pragma unroll
            for (int r = 0; r < 4; ++r) {
                float v = acc[tm][nt][r];
                int row = wm * 32 + tm * 16 + q4 * 4 + r;
                if (v > m1) { m2 = m1; i2 = i1; m1 = v; i1 = row; }
                else if (v > m2) { m2 = v; i2 = row; }
            }
#pragma unroll
        for (int off = 16; off < 64; off <<= 1) {
            float om1 = __shfl_xor(m1, off), om2 = __shfl_xor(m2, off);
            int oi1 = __shfl_xor(i1, off), oi2 = __shfl_xor(i2, off);
            bool take = (om1 > m1) || (om1 == m1 && oi1 < i1);
            float w1 = take ? om1 : m1; int wi1 = take ? oi1 : i1;
            float l1 = take ? m1 : om1; int li1 = take ? i1 : oi1;
            float s2 = m2; int si2 = i2;
            if (om2 > s2) { s2 = om2; si2 = oi2; }
            if (l1 > s2) { s2 = l1; si2 = li1; }
            m1 = w1; i1 = wi1; m2 = s2; i2 = si2;
        }
        if (q4 == 0) {
            int cw = (wn * 4 + nt) * 16 + lm;      // token col 0..127
            rm1[wm * 128 + cw] = m1; rm2[wm * 128 + cw] = m2;
            ri1[wm * 128 + cw] = i1; ri2[wm * 128 + cw] = i2;
        }
    }
    __syncthreads();
    if (tid < 128) {
        float a1 = rm1[tid], a2 = rm2[tid];
        int ai1 = ri1[tid], ai2 = ri2[tid];
        float b1 = rm1[128 + tid], b2 = rm2[128 + tid];
        int bi1 = ri1[128 + tid], bi2 = ri2[128 + tid];
        float w1, s2; int wi1, wi2;
        if (b1 > a1) { w1 = b1; wi1 = bi1; s2 = a1; wi2 = ai1; if (b2 > s2) { s2 = b2; wi2 = bi2; } }
        else         { w1 = a1; wi1 = ai1; s2 = a2; wi2 = ai2; if (b1 > s2) { s2 = b1; wi2 = bi1; } }
        idx[(size_t)(b * H_ + h) * S_ + s0 + tid] = (unsigned)wi1;
        if (w1 - s2 < TAU_) {
            unsigned p = atomicAdd(flag_cnt, 1u);
            if (p < LISTCAP) {
                unsigned tok = (unsigned)((b * H_ + h) * S_ + s0 + tid);
                flag_list[p] = tok | ((unsigned)wi1 << 19) | ((unsigned)wi2 << 25);
            }
        }
    }
}

// ---------------------------------------------------------------------------
// K3: fixup — exact fp32 recompute of two candidate rows for near-ties
// ---------------------------------------------------------------------------
__global__ __launch_bounds__(256) void fixup_kernel(const float* __restrict__ qk,
                                                    const float* __restrict__ key,
                                                    const unsigned int* __restrict__ flag_list,
                                                    const unsigned int* __restrict__ flag_cnt,
                                                    unsigned int* __restrict__ idx) {
    int w = threadIdx.x >> 6, l = threadIdx.x & 63;
    unsigned total = flag_cnt[0];
    if (total > LISTCAP) total = LISTCAP;
    for (unsigned t = blockIdx.x * 4 + w; t < total; t += gridDim.x * 4) {
        unsigned e = flag_list[t];
        unsigned tok = e & 0x7FFFFu;
        int i1 = (int)((e >> 19) & 63u), i2 = (int)((e >> 25) & 63u);
        unsigned bh = tok >> 12;
        unsigned s = tok & 4095u;
        unsigned bb = bh / H_;
        int l32 = l & 31;
        const float* qrow = qk + ((size_t)bh * N_ + (l < 32 ? i1 : i2)) * C_ + l32 * 12;
        const float* krow = key + ((size_t)bb * S_ + s) * C_ + l32 * 12;
        float sum = 0.f;
#pragma unroll
        for (int c = 0; c < 12; ++c) sum += qrow[c] * krow[c];
#pragma unroll
        for (int off = 1; off < 32; off <<= 1) sum += __shfl_xor(sum, off);
        float d1 = __shfl(sum, 0);
        float d2 = __shfl(sum, 32);
        int win = (d2 > d1 || (d2 == d1 && i2 < i1)) ? i2 : i1;
        if (l == 0) idx[(size_t)bh * S_ + s] = (unsigned)win;
    }
}

// ---------------------------------------------------------------------------
// K4: hist_build — 1024 threads (r11 state, kept)
// ---------------------------------------------------------------------------
__global__ __launch_bounds__(1024) void hist_build_kernel(const unsigned int* __restrict__ idx,
                                                          unsigned int* __restrict__ offs,
                                                          unsigned int* __restrict__ order) {
    __shared__ unsigned int cnts[N_];
    __shared__ unsigned int pos[N_];
    int tid = threadIdx.x;
    int bh = blockIdx.x;
    if (tid < N_) cnts[tid] = 0u;
    __syncthreads();
    const unsigned int* idxp = idx + (size_t)bh * S_;
    for (int s = tid; s < S_; s += 1024) atomicAdd(&cnts[idxp[s]], 1u);
    __syncthreads();
    if (tid < N_) {
        unsigned v = cnts[tid];
        unsigned x = v;
#pragma unroll
        for (int off = 1; off < 64; off <<= 1) {
            unsigned y = __shfl_up(x, off);
            if (tid >= off) x += y;
        }
        unsigned excl = x - v;
        pos[tid] = excl;
        offs[(size_t)bh * 65 + tid] = excl;
        if (tid == 63) offs[(size_t)bh * 65 + 64] = x;   // == S_
    }
    __syncthreads();
    unsigned int* op = order + (size_t)bh * S_;
    for (int s = tid; s < S_; s += 1024) {
        unsigned g = idxp[s];
        unsigned p = atomicAdd(&pos[g], 1u);
        op[p] = (unsigned)s;
    }
}

// ---------------------------------------------------------------------------
// K5+K6 fused: aggv — 8-part skew-proof gather on RAW FP32 key (r11 state,
// kept: exact sums -> absmax 0.00195) + coalesced WvT wave-split phase B.
// ---------------------------------------------------------------------------
#define AGG_PARTS 8
__global__ __launch_bounds__(512) void aggv_kernel(const float* __restrict__ key,
                                                   const unsigned int* __restrict__ order,
                                                   const unsigned int* __restrict__ offs,
                                                   const float* __restrict__ wvT,
                                                   float* __restrict__ gvn) {
    __shared__ float lrows[AGG_PARTS][C_];
    __shared__ float zrow[C_];
    __shared__ float pacc[AGG_PARTS][DH_];
    int tid = threadIdx.x;
    int part = tid >> 6, l = tid & 63;
    int h = blockIdx.y, b = blockIdx.z;
    int bh = b * H_ + h;
    int g = blockIdx.x;
    unsigned beg = offs[(size_t)bh * 65 + g];
    unsigned end = offs[(size_t)bh * 65 + g + 1];
    int cnt = (int)(end - beg);
    float inv = 1.f / ((float)cnt + 1.f);
    const unsigned int* op = order + (size_t)bh * S_ + beg;
    const float* kbase = key + (size_t)b * S_ * C_;
    float a0 = 0.f, a1 = 0.f, a2 = 0.f, a3 = 0.f, a4 = 0.f, a5 = 0.f;
    for (int base = part * 64; base < cnt; base += 64 * AGG_PARTS) {
        int m = cnt - base; if (m > 64) m = 64;
        unsigned sv = (l < m) ? op[base + l] : 0u;
        int i = 0;
        for (; i + 8 <= m; i += 8) {
            int ss[8];
#pragma unroll
            for (int j = 0; j < 8; ++j) ss[j] = __shfl((int)sv, i + j);
            float2 u[8][3];
#pragma unroll
            for (int j = 0; j < 8; ++j) {
                const float* kp = kbase + (size_t)ss[j] * C_ + l * 6;
                u[j][0] = *(const float2*)kp;
                u[j][1] = *(const float2*)(kp + 2);
                u[j][2] = *(const float2*)(kp + 4);
            }
#pragma unroll
            for (int j = 0; j < 8; ++j) {
                a0 += u[j][0].x; a1 += u[j][0].y;
                a2 += u[j][1].x; a3 += u[j][1].y;
                a4 += u[j][2].x; a5 += u[j][2].y;
            }
        }
        for (; i < m; ++i) {
            int s = (int)__shfl((int)sv, i);
            const float* kp = kbase + (size_t)s * C_ + l * 6;
            float2 u0 = *(const float2*)kp;
            float2 u1 = *(const float2*)(kp + 2);
            float2 u2 = *(const float2*)(kp + 4);
            a0 += u0.x; a1 += u0.y; a2 += u1.x;
            a3 += u1.y; a4 += u2.x; a5 += u2.y;
        }
    }
    float* lp = &lrows[part][l * 6];
    lp[0] = a0 * inv; lp[1] = a1 * inv; lp[2] = a2 * inv;
    lp[3] = a3 * inv; lp[4] = a4 * inv; lp[5] = a5 * inv;
    __syncthreads();
    if (tid < C_) {
        float z = lrows[0][tid];
#pragma unroll
        for (int p = 1; p < AGG_PARTS; ++p) z += lrows[p][tid];
        zrow[tid] = z;
    }
    __syncthreads();
    {
        float a = 0.f;
        int cb = part * (C_ / AGG_PARTS);
#pragma unroll 8
        for (int cc = 0; cc < C_ / AGG_PARTS; ++cc) {
            int c = cb + cc;
            a += zrow[c] * wvT[(size_t)c * C_ + h * DH_ + l];
        }
        pacc[part][l] = a;
    }
    __syncthreads();
    if (part == 0) {
        float acc = pacc[0][l];
#pragma unroll
        for (int p = 1; p < AGG_PARTS; ++p) acc += pacc[p][l];
        gvn[((size_t)bh * N_ + g) * DH_ + l] = acc;
    }
}

// ---------------------------------------------------------------------------
// K7: out — 1024 blocks, WpT coalesced (r9 state, known-good)
// ---------------------------------------------------------------------------
__global__ __launch_bounds__(384) void out_kernel(const float* __restrict__ gvn,
                                                  const float* __restrict__ wpT,
                                                  const float* __restrict__ bp,
                                                  float* __restrict__ out) {
    __shared__ float vals[C_];
    int bn = blockIdx.x;                  // 0..1023
    int b = bn >> 6, n = bn & 63;
    int t = threadIdx.x;
    int h = t >> 6, d = t & 63;
    vals[t] = gvn[((size_t)(b * H_ + h) * N_ + n) * DH_ + d];
    __syncthreads();
    float s = bp[t];
#pragma unroll 8
    for (int c = 0; c < C_; ++c)
        s += vals[c] * wpT[(size_t)c * C_ + t];
    out[(size_t)bn * C_ + t] = s;
}

// ---------------------------------------------------------------------------
extern "C" void kernel_launch(void* const* d_in, const int* in_sizes, int n_in,
                              void* d_out, int out_size, void* d_ws, size_t ws_size,
                              hipStream_t stream) {
    (void)in_sizes; (void)n_in; (void)out_size; (void)ws_size;
    const float* query = (const float*)d_in[0];
    const float* key   = (const float*)d_in[1];
    const float* Wq    = (const float*)d_in[2];
    const float* Wk    = (const float*)d_in[3];
    const float* Wv    = (const float*)d_in[4];
    const float* Wp    = (const float*)d_in[5];
    const float* bp    = (const float*)d_in[6];
    float* out = (float*)d_out;

    char* ws = (char*)d_ws;
    size_t off = 0;
    unsigned short* khi  = (unsigned short*)(ws + off); off += (size_t)B_ * S_ * C_ * 2;
    unsigned short* klo  = (unsigned short*)(ws + off); off += (size_t)B_ * S_ * C_ * 2;
    float* qk            = (float*)(ws + off);          off += (size_t)B_ * H_ * N_ * C_ * 4;
    unsigned short* qkhi = (unsigned short*)(ws + off); off += (size_t)B_ * H_ * N_ * C_ * 2;
    unsigned short* qklo = (unsigned short*)(ws + off); off += (size_t)B_ * H_ * N_ * C_ * 2;
    unsigned int* idx    = (unsigned int*)(ws + off);   off += (size_t)B_ * H_ * S_ * 4;
    unsigned int* order  = (unsigned int*)(ws + off);   off += (size_t)B_ * H_ * S_ * 4;
    unsigned int* offs   = (unsigned int*)(ws + off);   off += (size_t)B_ * H_ * 65 * 4;
    float* gvn           = (float*)(ws + off);          off += (size_t)B_ * H_ * N_ * DH_ * 4;
    float* wpT           = (float*)(ws + off);          off += (size_t)C_ * C_ * 4;
    float* wvT           = (float*)(ws + off);          off += (size_t)C_ * C_ * 4;
    unsigned int* fcnt   = (unsigned int*)(ws + off);   off += 256;
    unsigned int* flist  = (unsigned int*)(ws + off);   off += (size_t)LISTCAP * 4;

    hipMemsetAsync(fcnt, 0, 256, stream);

    prepqk_kernel<<<PREP_BLOCKS + QK_BLOCKS + TR_BLOCKS, 384, 0, stream>>>(
        key, khi, klo, query, Wq, Wk, qk, qkhi, qklo, Wp, Wv, wpT, wvT);
    attn_kernel<<<dim3(S_ / 128, H_, B_), 256, 0, stream>>>(qkhi, qklo, khi, klo, idx, fcnt, flist);
    fixup_kernel<<<256, 256, 0, stream>>>(qk, key, flist, fcnt, idx);
    hist_build_kernel<<<B_ * H_, 1024, 0, stream>>>(idx, offs, order);
    aggv_kernel<<<dim3(N_, H_, B_), 512, 0, stream>>>(key, order, offs, wvT, gvn);
    out_kernel<<<B_ * N_, 384, 0, stream>>>(gvn, wpT, bp, out);
}

// Round 14
// 373.824 us; speedup vs baseline: 1.0406x; 1.0406x over previous
//
#include <hip/hip_runtime.h>
#include <hip/hip_bf16.h>
#include <stdint.h>

#define B_ 16
#define N_ 64
#define S_ 4096
#define C_ 384
#define H_ 6
#define DH_ 64
#define SCALE_ 0.125f
#define TAU_ 2e-4f
#define LISTCAP 262144

typedef __attribute__((ext_vector_type(8))) short bf16x8;
typedef __attribute__((ext_vector_type(4))) float f32x4;
typedef __attribute__((ext_vector_type(4))) unsigned short u16x4;

static __device__ __forceinline__ unsigned short f2bf(float x) {
    union { float f; unsigned u; } v; v.f = x;
    unsigned r = v.u + 0x7FFFu + ((v.u >> 16) & 1u);
    return (unsigned short)(r >> 16);
}
static __device__ __forceinline__ float bf2f(unsigned short b) {
    union { unsigned u; float f; } v; v.u = ((unsigned)b) << 16; return v.f;
}
static __device__ __forceinline__ float bfu_lo(unsigned u) {
    union { unsigned u; float f; } v; v.u = u << 16; return v.f;
}
static __device__ __forceinline__ float bfu_hi(unsigned u) {
    union { unsigned u; float f; } v; v.u = u & 0xFFFF0000u; return v.f;
}

// async global->LDS, 16B/lane; LDS dest = wave-uniform base + lane*16
static __device__ __forceinline__ void gl_lds16(const void* g, void* l) {
    __builtin_amdgcn_global_load_lds(
        (const __attribute__((address_space(1))) unsigned int*)g,
        (__attribute__((address_space(3))) unsigned int*)l, 16, 0, 0);
}

// ---------------------------------------------------------------------------
// K0+K1 fused: prep (coalesced) + qk (LDS-staged Wq) + Wp/Wv transposes.
// (r13 state, known-good)
// ---------------------------------------------------------------------------
#define PREP_BLOCKS 8192   // 8192 * 3072 elems = 16*4096*384
#define QK_BLOCKS   (8 * H_ * B_)   // 768
#define TR_BLOCKS   72              // 2 matrices x 36 (64x64) tiles

#define TRT(r, c) sbuf[(r) * 65 + (c)]
#define WQS(d, c) sbuf[(d) * 49 + (c)]

__global__ __launch_bounds__(384) void prepqk_kernel(const float* __restrict__ key,
                                                     unsigned short* __restrict__ khi,
                                                     unsigned short* __restrict__ klo,
                                                     const float* __restrict__ query,
                                                     const float* __restrict__ Wq,
                                                     const float* __restrict__ Wk,
                                                     float* __restrict__ qk,
                                                     unsigned short* __restrict__ qkhi,
                                                     unsigned short* __restrict__ qklo,
                                                     const float* __restrict__ Wp,
                                                     const float* __restrict__ Wv,
                                                     float* __restrict__ wpT,
                                                     float* __restrict__ wvT) {
    __shared__ float qstage[8][C_];
    __shared__ float qv[8][DH_];
    __shared__ float sbuf[64 * 65];
    int t = threadIdx.x;
    if (blockIdx.x < PREP_BLOCKS) {
        size_t blk = (size_t)blockIdx.x * 3072;
#pragma unroll
        for (int half = 0; half < 2; ++half) {
            size_t base = blk + (size_t)half * 1536 + (size_t)t * 4;
            float4 x = *(const float4*)(key + base);
            float xs[4] = { x.x, x.y, x.z, x.w };
            unsigned short hi[4], lo[4];
#pragma unroll
            for (int i = 0; i < 4; ++i) {
                hi[i] = f2bf(xs[i]);
                lo[i] = f2bf(xs[i] - bf2f(hi[i]));
            }
            *(u16x4*)(khi + base) = *(u16x4*)hi;
            *(u16x4*)(klo + base) = *(u16x4*)lo;
        }
        return;
    }
    int e = blockIdx.x - PREP_BLOCKS;
    if (e >= QK_BLOCKS) {
        int e2 = e - QK_BLOCKS;                 // 0..71
        const float* src = (e2 < 36) ? Wp : Wv;
        float* dst = (e2 < 36) ? wpT : wvT;
        int tile = e2 % 36;
        int r0 = (tile / 6) * 64, c0 = (tile % 6) * 64;
        if (t < 256) {
#pragma unroll
            for (int rep = 0; rep < 16; ++rep) {
                int idx = rep * 256 + t;
                int r = idx >> 6, c = idx & 63;
                TRT(r, c) = src[(size_t)(r0 + r) * C_ + c0 + c];
            }
        }
        __syncthreads();
        if (t < 256) {
#pragma unroll
            for (int rep = 0; rep < 16; ++rep) {
                int idx = rep * 256 + t;
                int rT = idx >> 6, cT = idx & 63;
                dst[(size_t)(c0 + rT) * C_ + r0 + cT] = TRT(cT, rT);
            }
        }
        return;
    }
    // ---- qk part ----
    int ng = e & 7;
    int h = (e >> 3) % H_;
    int b = e / (8 * H_);
    int n0 = ng * 8;
#pragma unroll
    for (int i = 0; i < 8; ++i)
        qstage[i][t] = query[((size_t)(b * N_ + n0 + i)) * C_ + t];
    {
        int i0 = (t < 256) ? (t >> 6) : 0;
        int d = t & 63;
        float accA = 0.f, accB = 0.f;
        for (int c0 = 0; c0 < C_; c0 += 48) {
            __syncthreads();
#pragma unroll
            for (int rep = 0; rep < 8; ++rep) {
                int idx2 = rep * 384 + t;
                int r = idx2 / 48, c = idx2 % 48;
                WQS(r, c) = Wq[(size_t)(h * DH_ + r) * C_ + c0 + c];
            }
            __syncthreads();
            if (t < 256) {
#pragma unroll
                for (int cc = 0; cc < 48; cc += 4) {
                    accA += qstage[i0][c0 + cc + 0] * WQS(d, cc + 0)
                          + qstage[i0][c0 + cc + 1] * WQS(d, cc + 1)
                          + qstage[i0][c0 + cc + 2] * WQS(d, cc + 2)
                          + qstage[i0][c0 + cc + 3] * WQS(d, cc + 3);
                    accB += qstage[i0 + 4][c0 + cc + 0] * WQS(d, cc + 0)
                          + qstage[i0 + 4][c0 + cc + 1] * WQS(d, cc + 1)
                          + qstage[i0 + 4][c0 + cc + 2] * WQS(d, cc + 2)
                          + qstage[i0 + 4][c0 + cc + 3] * WQS(d, cc + 3);
                }
            }
        }
        if (t < 256) {
            qv[i0][d] = accA * SCALE_;
            qv[i0 + 4][d] = accB * SCALE_;
        }
    }
    __syncthreads();
    float a[8];
#pragma unroll
    for (int i = 0; i < 8; ++i) a[i] = 0.f;
    {
        const float* wk = Wk + (size_t)h * DH_ * C_ + t;
#pragma unroll 4
        for (int d = 0; d < DH_; ++d) {
            float w = wk[(size_t)d * C_];
#pragma unroll
            for (int i = 0; i < 8; ++i) a[i] += qv[i][d] * w;
        }
    }
#pragma unroll
    for (int i = 0; i < 8; ++i) qstage[i][t] = a[i];
    __syncthreads();
    {
        int r = t / 48, c0 = (t % 48) * 8;
        float v[8];
#pragma unroll
        for (int j = 0; j < 8; ++j) v[j] = qstage[r][c0 + j];
        unsigned short hi[8], lo[8];
#pragma unroll
        for (int j = 0; j < 8; ++j) {
            hi[j] = f2bf(v[j]);
            lo[j] = f2bf(v[j] - bf2f(hi[j]));
        }
        size_t o = ((size_t)(b * H_ + h) * N_ + n0 + r) * C_ + c0;
        float4 f0 = { v[0], v[1], v[2], v[3] };
        float4 f1 = { v[4], v[5], v[6], v[7] };
        *(float4*)(qk + o) = f0;
        *(float4*)(qk + o + 4) = f1;
        *(bf16x8*)(qkhi + o) = *(bf16x8*)hi;
        *(bf16x8*)(qklo + o) = *(bf16x8*)lo;
    }
}

// ---------------------------------------------------------------------------
// K2: attn — ROUND-THIS: double-buffer RETRY at the 128-token tile.
// r1's dbuf failed at 256-tile via occupancy cliffs (80KB->2 blk/CU, VGPR
// 148). Here: 2x24KB=48KB -> 3 blk/CU = 12 waves/CU = 37.5% cap, ABOVE
// the measured 29.6% occupancy (residency not LDS-limited), VGPR 72+~16
// dual-address ~88 < 102 cliff -> no cliff crossed. Structure: STAGE(next)
// issued BEFORE frag-reads+MFMA of current; one vmcnt(0)+lgkmcnt(0)+
// sched_barrier(0)+s_barrier per K-step (rule #18 fence). Hazard: buf
// written at t was last read at t-1, drained by that iteration's wait+
// barrier. MFMA inputs/order unchanged -> idx bit-identical.
// ---------------------------------------------------------------------------
__global__ __launch_bounds__(256) void attn_kernel(const unsigned short* __restrict__ qkhi,
                                                   const unsigned short* __restrict__ qklo,
                                                   const unsigned short* __restrict__ khi,
                                                   const unsigned short* __restrict__ klo,
                                                   unsigned int* __restrict__ idx,
                                                   unsigned int* __restrict__ flag_cnt,
                                                   unsigned int* __restrict__ flag_list) {
    __shared__ __align__(16) unsigned short sAhi[2][64 * 32];
    __shared__ __align__(16) unsigned short sAlo[2][64 * 32];
    __shared__ __align__(16) unsigned short sBhi[2][128 * 32];
    __shared__ __align__(16) unsigned short sBlo[2][128 * 32];
    int tid = threadIdx.x;
    int w = tid >> 6, l = tid & 63;
    int wm = w >> 1, wn = w & 1;
    int q4 = l >> 4, lm = l & 15;
    int s0 = blockIdx.x * 128;
    int h = blockIdx.y, b = blockIdx.z;
    size_t kbK = ((size_t)b * S_ + s0) * C_;
    size_t kbA = (size_t)(b * H_ + h) * N_ * C_;
    int trow16 = l >> 2;
    int tquart = ((l & 3) ^ ((l >> 3) & 3)) * 8;
    int sw = (q4 ^ ((lm >> 1) & 3)) * 8;

    f32x4 acc[2][4];
#pragma unroll
    for (int tm = 0; tm < 2; ++tm)
#pragma unroll
        for (int nt = 0; nt < 4; ++nt) acc[tm][nt] = (f32x4)0.f;

// per-wave 6 async loads for K-chunk `kc` into buffer `buf`
#define STAGE(buf, kc)                                                                   \
    do {                                                                                 \
        _Pragma("unroll")                                                                \
        for (int i_ = 0; i_ < 6; ++i_) {                                                 \
            int gid = w * 6 + i_;                                                        \
            if (gid < 8) {                                                               \
                gl_lds16(khi + kbK + (size_t)(gid * 16 + trow16) * C_ + (kc) + tquart,   \
                         (char*)sBhi[buf] + gid * 1024);                                 \
            } else if (gid < 16) {                                                       \
                int g2 = gid - 8;                                                        \
                gl_lds16(klo + kbK + (size_t)(g2 * 16 + trow16) * C_ + (kc) + tquart,    \
                         (char*)sBlo[buf] + g2 * 1024);                                  \
            } else if (gid < 20) {                                                       \
                int g2 = gid - 16;                                                       \
                gl_lds16(qkhi + kbA + (size_t)(g2 * 16 + trow16) * C_ + (kc) + tquart,   \
                         (char*)sAhi[buf] + g2 * 1024);                                  \
            } else {                                                                     \
                int g2 = gid - 20;                                                       \
                gl_lds16(qklo + kbA + (size_t)(g2 * 16 + trow16) * C_ + (kc) + tquart,   \
                         (char*)sAlo[buf] + g2 * 1024);                                  \
            }                                                                            \
        }                                                                                \
    } while (0)

    STAGE(0, 0);
    asm volatile("s_waitcnt vmcnt(0)" ::: "memory");
    __builtin_amdgcn_s_barrier();

    for (int t = 0; t < C_ / 32; ++t) {
        int cur = t & 1;
        if (t + 1 < C_ / 32) STAGE(cur ^ 1, (t + 1) * 32);

        bf16x8 ah[2], al[2];
#pragma unroll
        for (int tm = 0; tm < 2; ++tm) {
            int ar = (wm * 32 + tm * 16 + lm) * 32 + sw;
            ah[tm] = *(const bf16x8*)&sAhi[cur][ar];
            al[tm] = *(const bf16x8*)&sAlo[cur][ar];
        }
#pragma unroll
        for (int nt = 0; nt < 4; ++nt) {
            int nr = ((wn * 4 + nt) * 16 + lm) * 32 + sw;
            bf16x8 bh = *(const bf16x8*)&sBhi[cur][nr];
            bf16x8 bl = *(const bf16x8*)&sBlo[cur][nr];
#pragma unroll
            for (int tm = 0; tm < 2; ++tm) {
                acc[tm][nt] = __builtin_amdgcn_mfma_f32_16x16x32_bf16(ah[tm], bh, acc[tm][nt], 0, 0, 0);
                acc[tm][nt] = __builtin_amdgcn_mfma_f32_16x16x32_bf16(ah[tm], bl, acc[tm][nt], 0, 0, 0);
                acc[tm][nt] = __builtin_amdgcn_mfma_f32_16x16x32_bf16(al[tm], bh, acc[tm][nt], 0, 0, 0);
            }
        }
        asm volatile("s_waitcnt vmcnt(0) lgkmcnt(0)" ::: "memory");
        __builtin_amdgcn_sched_barrier(0);
        __builtin_amdgcn_s_barrier();
    }
#undef STAGE
    __syncthreads();

    float* rm1 = (float*)sBhi;   // scratch aliases sBhi[0]; safe after final barrier
    float* rm2 = rm1 + 256;
    int* ri1 = (int*)(rm2 + 256);
    int* ri2 = ri1 + 256;

#pragma unroll
    for (int nt = 0; nt < 4; ++nt) {
        float m1 = -3.4e38f, m2 = -3.4e38f; int i1 = 0, i2 = 0;
#pragma unroll
        for (int tm = 0; tm < 2; ++tm)
#pragma unroll
            for (int r = 0; r < 4; ++r) {
                float v = acc[tm][nt][r];
                int row = wm * 32 + tm * 16 + q4 * 4 + r;
                if (v > m1) { m2 = m1; i2 = i1; m1 = v; i1 = row; }
                else if (v > m2) { m2 = v; i2 = row; }
            }
#pragma unroll
        for (int off = 16; off < 64; off <<= 1) {
            float om1 = __shfl_xor(m1, off), om2 = __shfl_xor(m2, off);
            int oi1 = __shfl_xor(i1, off), oi2 = __shfl_xor(i2, off);
            bool take = (om1 > m1) || (om1 == m1 && oi1 < i1);
            float w1 = take ? om1 : m1; int wi1 = take ? oi1 : i1;
            float l1 = take ? m1 : om1; int li1 = take ? i1 : oi1;
            float s2 = m2; int si2 = i2;
            if (om2 > s2) { s2 = om2; si2 = oi2; }
            if (l1 > s2) { s2 = l1; si2 = li1; }
            m1 = w1; i1 = wi1; m2 = s2; i2 = si2;
        }
        if (q4 == 0) {
            int cw = (wn * 4 + nt) * 16 + lm;      // token col 0..127
            rm1[wm * 128 + cw] = m1; rm2[wm * 128 + cw] = m2;
            ri1[wm * 128 + cw] = i1; ri2[wm * 128 + cw] = i2;
        }
    }
    __syncthreads();
    if (tid < 128) {
        float a1 = rm1[tid], a2 = rm2[tid];
        int ai1 = ri1[tid], ai2 = ri2[tid];
        float b1 = rm1[128 + tid], b2 = rm2[128 + tid];
        int bi1 = ri1[128 + tid], bi2 = ri2[128 + tid];
        float w1, s2; int wi1, wi2;
        if (b1 > a1) { w1 = b1; wi1 = bi1; s2 = a1; wi2 = ai1; if (b2 > s2) { s2 = b2; wi2 = bi2; } }
        else         { w1 = a1; wi1 = ai1; s2 = a2; wi2 = ai2; if (b1 > s2) { s2 = b1; wi2 = bi1; } }
        idx[(size_t)(b * H_ + h) * S_ + s0 + tid] = (unsigned)wi1;
        if (w1 - s2 < TAU_) {
            unsigned p = atomicAdd(flag_cnt, 1u);
            if (p < LISTCAP) {
                unsigned tok = (unsigned)((b * H_ + h) * S_ + s0 + tid);
                flag_list[p] = tok | ((unsigned)wi1 << 19) | ((unsigned)wi2 << 25);
            }
        }
    }
}

// ---------------------------------------------------------------------------
// K3: fixup — exact fp32 recompute of two candidate rows for near-ties
// ---------------------------------------------------------------------------
__global__ __launch_bounds__(256) void fixup_kernel(const float* __restrict__ qk,
                                                    const float* __restrict__ key,
                                                    const unsigned int* __restrict__ flag_list,
                                                    const unsigned int* __restrict__ flag_cnt,
                                                    unsigned int* __restrict__ idx) {
    int w = threadIdx.x >> 6, l = threadIdx.x & 63;
    unsigned total = flag_cnt[0];
    if (total > LISTCAP) total = LISTCAP;
    for (unsigned t = blockIdx.x * 4 + w; t < total; t += gridDim.x * 4) {
        unsigned e = flag_list[t];
        unsigned tok = e & 0x7FFFFu;
        int i1 = (int)((e >> 19) & 63u), i2 = (int)((e >> 25) & 63u);
        unsigned bh = tok >> 12;
        unsigned s = tok & 4095u;
        unsigned bb = bh / H_;
        int l32 = l & 31;
        const float* qrow = qk + ((size_t)bh * N_ + (l < 32 ? i1 : i2)) * C_ + l32 * 12;
        const float* krow = key + ((size_t)bb * S_ + s) * C_ + l32 * 12;
        float sum = 0.f;
#pragma unroll
        for (int c = 0; c < 12; ++c) sum += qrow[c] * krow[c];
#pragma unroll
        for (int off = 1; off < 32; off <<= 1) sum += __shfl_xor(sum, off);
        float d1 = __shfl(sum, 0);
        float d2 = __shfl(sum, 32);
        int win = (d2 > d1 || (d2 == d1 && i2 < i1)) ? i2 : i1;
        if (l == 0) idx[(size_t)bh * S_ + s] = (unsigned)win;
    }
}

// ---------------------------------------------------------------------------
// K4: hist_build — reverted to 256 threads (r10 form; the 1024-thread
// variant was part of the r13 ~11us regression bundle)
// ---------------------------------------------------------------------------
__global__ __launch_bounds__(256) void hist_build_kernel(const unsigned int* __restrict__ idx,
                                                         unsigned int* __restrict__ offs,
                                                         unsigned int* __restrict__ order) {
    __shared__ unsigned int cnts[N_];
    __shared__ unsigned int pos[N_];
    int tid = threadIdx.x;
    int bh = blockIdx.x;
    if (tid < N_) cnts[tid] = 0u;
    __syncthreads();
    const unsigned int* idxp = idx + (size_t)bh * S_;
    for (int s = tid; s < S_; s += 256) atomicAdd(&cnts[idxp[s]], 1u);
    __syncthreads();
    if (tid < N_) {
        unsigned v = cnts[tid];
        unsigned x = v;
#pragma unroll
        for (int off = 1; off < 64; off <<= 1) {
            unsigned y = __shfl_up(x, off);
            if (tid >= off) x += y;
        }
        unsigned excl = x - v;
        pos[tid] = excl;
        offs[(size_t)bh * 65 + tid] = excl;
        if (tid == 63) offs[(size_t)bh * 65 + 64] = x;   // == S_
    }
    __syncthreads();
    unsigned int* op = order + (size_t)bh * S_;
    for (int s = tid; s < S_; s += 256) {
        unsigned g = idxp[s];
        unsigned p = atomicAdd(&pos[g], 1u);
        op[p] = (unsigned)s;
    }
}

// ---------------------------------------------------------------------------
// K5+K6 fused: aggv — reverted to r10 form: 8-part skew-proof gather on
// khi (bf16, HALF the gather bytes of the r11 fp32 variant — the other
// part of the r13 regression bundle) + coalesced WvT wave-split phase B.
// ---------------------------------------------------------------------------
#define AGG_PARTS 8
__global__ __launch_bounds__(512) void aggv_kernel(const unsigned short* __restrict__ khi,
                                                   const unsigned int* __restrict__ order,
                                                   const unsigned int* __restrict__ offs,
                                                   const float* __restrict__ wvT,
                                                   float* __restrict__ gvn) {
    __shared__ float lrows[AGG_PARTS][C_];
    __shared__ float zrow[C_];
    __shared__ float pacc[AGG_PARTS][DH_];
    int tid = threadIdx.x;
    int part = tid >> 6, l = tid & 63;
    int h = blockIdx.y, b = blockIdx.z;
    int bh = b * H_ + h;
    int g = blockIdx.x;
    unsigned beg = offs[(size_t)bh * 65 + g];
    unsigned end = offs[(size_t)bh * 65 + g + 1];
    int cnt = (int)(end - beg);
    float inv = 1.f / ((float)cnt + 1.f);
    const unsigned int* op = order + (size_t)bh * S_ + beg;
    const unsigned int* kbase = (const unsigned int*)(khi + (size_t)b * S_ * C_);
    float a0 = 0.f, a1 = 0.f, a2 = 0.f, a3 = 0.f, a4 = 0.f, a5 = 0.f;
    for (int base = part * 64; base < cnt; base += 64 * AGG_PARTS) {
        int m = cnt - base; if (m > 64) m = 64;
        unsigned sv = (l < m) ? op[base + l] : 0u;
        int i = 0;
        for (; i + 8 <= m; i += 8) {
            int ss[8];
#pragma unroll
            for (int j = 0; j < 8; ++j) ss[j] = __shfl((int)sv, i + j);
            unsigned u[8][3];
#pragma unroll
            for (int j = 0; j < 8; ++j) {
                const unsigned int* kp = kbase + (size_t)ss[j] * (C_ / 2) + l * 3;
                u[j][0] = kp[0]; u[j][1] = kp[1]; u[j][2] = kp[2];
            }
#pragma unroll
            for (int j = 0; j < 8; ++j) {
                a0 += bfu_lo(u[j][0]); a1 += bfu_hi(u[j][0]);
                a2 += bfu_lo(u[j][1]); a3 += bfu_hi(u[j][1]);
                a4 += bfu_lo(u[j][2]); a5 += bfu_hi(u[j][2]);
            }
        }
        for (; i < m; ++i) {
            int s = (int)__shfl((int)sv, i);
            const unsigned int* kp = kbase + (size_t)s * (C_ / 2) + l * 3;
            unsigned u0 = kp[0], u1 = kp[1], u2 = kp[2];
            a0 += bfu_lo(u0); a1 += bfu_hi(u0);
            a2 += bfu_lo(u1); a3 += bfu_hi(u1);
            a4 += bfu_lo(u2); a5 += bfu_hi(u2);
        }
    }
    float* lp = &lrows[part][l * 6];
    lp[0] = a0 * inv; lp[1] = a1 * inv; lp[2] = a2 * inv;
    lp[3] = a3 * inv; lp[4] = a4 * inv; lp[5] = a5 * inv;
    __syncthreads();
    if (tid < C_) {
        float z = lrows[0][tid];
#pragma unroll
        for (int p = 1; p < AGG_PARTS; ++p) z += lrows[p][tid];
        zrow[tid] = z;
    }
    __syncthreads();
    {
        float a = 0.f;
        int cb = part * (C_ / AGG_PARTS);
#pragma unroll 8
        for (int cc = 0; cc < C_ / AGG_PARTS; ++cc) {
            int c = cb + cc;
            a += zrow[c] * wvT[(size_t)c * C_ + h * DH_ + l];
        }
        pacc[part][l] = a;
    }
    __syncthreads();
    if (part == 0) {
        float acc = pacc[0][l];
#pragma unroll
        for (int p = 1; p < AGG_PARTS; ++p) acc += pacc[p][l];
        gvn[((size_t)bh * N_ + g) * DH_ + l] = acc;
    }
}

// ---------------------------------------------------------------------------
// K7: out — 1024 blocks, WpT coalesced (r9 state, known-good)
// ---------------------------------------------------------------------------
__global__ __launch_bounds__(384) void out_kernel(const float* __restrict__ gvn,
                                                  const float* __restrict__ wpT,
                                                  const float* __restrict__ bp,
                                                  float* __restrict__ out) {
    __shared__ float vals[C_];
    int bn = blockIdx.x;                  // 0..1023
    int b = bn >> 6, n = bn & 63;
    int t = threadIdx.x;
    int h = t >> 6, d = t & 63;
    vals[t] = gvn[((size_t)(b * H_ + h) * N_ + n) * DH_ + d];
    __syncthreads();
    float s = bp[t];
#pragma unroll 8
    for (int c = 0; c < C_; ++c)
        s += vals[c] * wpT[(size_t)c * C_ + t];
    out[(size_t)bn * C_ + t] = s;
}

// ---------------------------------------------------------------------------
extern "C" void kernel_launch(void* const* d_in, const int* in_sizes, int n_in,
                              void* d_out, int out_size, void* d_ws, size_t ws_size,
                              hipStream_t stream) {
    (void)in_sizes; (void)n_in; (void)out_size; (void)ws_size;
    const float* query = (const float*)d_in[0];
    const float* key   = (const float*)d_in[1];
    const float* Wq    = (const float*)d_in[2];
    const float* Wk    = (const float*)d_in[3];
    const float* Wv    = (const float*)d_in[4];
    const float* Wp    = (const float*)d_in[5];
    const float* bp    = (const float*)d_in[6];
    float* out = (float*)d_out;

    char* ws = (char*)d_ws;
    size_t off = 0;
    unsigned short* khi  = (unsigned short*)(ws + off); off += (size_t)B_ * S_ * C_ * 2;
    unsigned short* klo  = (unsigned short*)(ws + off); off += (size_t)B_ * S_ * C_ * 2;
    float* qk            = (float*)(ws + off);          off += (size_t)B_ * H_ * N_ * C_ * 4;
    unsigned short* qkhi = (unsigned short*)(ws + off); off += (size_t)B_ * H_ * N_ * C_ * 2;
    unsigned short* qklo = (unsigned short*)(ws + off); off += (size_t)B_ * H_ * N_ * C_ * 2;
    unsigned int* idx    = (unsigned int*)(ws + off);   off += (size_t)B_ * H_ * S_ * 4;
    unsigned int* order  = (unsigned int*)(ws + off);   off += (size_t)B_ * H_ * S_ * 4;
    unsigned int* offs   = (unsigned int*)(ws + off);   off += (size_t)B_ * H_ * 65 * 4;
    float* gvn           = (float*)(ws + off);          off += (size_t)B_ * H_ * N_ * DH_ * 4;
    float* wpT           = (float*)(ws + off);          off += (size_t)C_ * C_ * 4;
    float* wvT           = (float*)(ws + off);          off += (size_t)C_ * C_ * 4;
    unsigned int* fcnt   = (unsigned int*)(ws + off);   off += 256;
    unsigned int* flist  = (unsigned int*)(ws + off);   off += (size_t)LISTCAP * 4;

    hipMemsetAsync(fcnt, 0, 256, stream);

    prepqk_kernel<<<PREP_BLOCKS + QK_BLOCKS + TR_BLOCKS, 384, 0, stream>>>(
        key, khi, klo, query, Wq, Wk, qk, qkhi, qklo, Wp, Wv, wpT, wvT);
    attn_kernel<<<dim3(S_ / 128, H_, B_), 256, 0, stream>>>(qkhi, qklo, khi, klo, idx, fcnt, flist);
    fixup_kernel<<<256, 256, 0, stream>>>(qk, key, flist, fcnt, idx);
    hist_build_kernel<<<B_ * H_, 256, 0, stream>>>(idx, offs, order);
    aggv_kernel<<<dim3(N_, H_, B_), 512, 0, stream>>>(khi, order, offs, wvT, gvn);
    out_kernel<<<B_ * N_, 384, 0, stream>>>(gvn, wpT, bp, out);
}

// Round 15
// 372.874 us; speedup vs baseline: 1.0432x; 1.0025x over previous
//
#include <hip/hip_runtime.h>
#include <hip/hip_bf16.h>
#include <stdint.h>

#define B_ 16
#define N_ 64
#define S_ 4096
#define C_ 384
#define H_ 6
#define DH_ 64
#define SCALE_ 0.125f
#define TAU_ 2e-4f
#define LISTCAP 262144

typedef __attribute__((ext_vector_type(8))) short bf16x8;
typedef __attribute__((ext_vector_type(4))) float f32x4;
typedef __attribute__((ext_vector_type(4))) unsigned short u16x4;

static __device__ __forceinline__ unsigned short f2bf(float x) {
    union { float f; unsigned u; } v; v.f = x;
    unsigned r = v.u + 0x7FFFu + ((v.u >> 16) & 1u);
    return (unsigned short)(r >> 16);
}
static __device__ __forceinline__ float bf2f(unsigned short b) {
    union { unsigned u; float f; } v; v.u = ((unsigned)b) << 16; return v.f;
}
static __device__ __forceinline__ float bfu_lo(unsigned u) {
    union { unsigned u; float f; } v; v.u = u << 16; return v.f;
}
static __device__ __forceinline__ float bfu_hi(unsigned u) {
    union { unsigned u; float f; } v; v.u = u & 0xFFFF0000u; return v.f;
}

// async global->LDS, 16B/lane; LDS dest = wave-uniform base + lane*16
static __device__ __forceinline__ void gl_lds16(const void* g, void* l) {
    __builtin_amdgcn_global_load_lds(
        (const __attribute__((address_space(1))) unsigned int*)g,
        (__attribute__((address_space(3))) unsigned int*)l, 16, 0, 0);
}

// ---------------------------------------------------------------------------
// K0: prep (key->khi/klo, coalesced) + Wp/Wv/Wk transpose tiles.
// ROUND-THIS (split for isolation): prepqk sat at ~107us through THREE
// targeted fixes (r7 null, r9 null, r10 -9us) — per-half attribution is
// broken while they share one dispatch. Split gives clean counters: prep
// HBM math says ~35-50us; if it shows 70+, the prep half was the mystery.
// Wk transpose ADDED here (36 tiles) so qk_kernel can read WkT rows
// vectorized; produced strictly before qk_kernel launches (stream order).
// ---------------------------------------------------------------------------
#define PREP_BLOCKS 8192   // 8192 * 3072 elems = 16*4096*384
#define TR_BLOCKS   108    // 3 matrices x 36 (64x64) tiles

__global__ __launch_bounds__(384) void prep_kernel(const float* __restrict__ key,
                                                   unsigned short* __restrict__ khi,
                                                   unsigned short* __restrict__ klo,
                                                   const float* __restrict__ Wp,
                                                   const float* __restrict__ Wv,
                                                   const float* __restrict__ Wk,
                                                   float* __restrict__ wpT,
                                                   float* __restrict__ wvT,
                                                   float* __restrict__ wkT) {
    __shared__ float trt[64][65];
    int t = threadIdx.x;
    if (blockIdx.x < PREP_BLOCKS) {
        size_t blk = (size_t)blockIdx.x * 3072;
#pragma unroll
        for (int half = 0; half < 2; ++half) {
            size_t base = blk + (size_t)half * 1536 + (size_t)t * 4;
            float4 x = *(const float4*)(key + base);
            float xs[4] = { x.x, x.y, x.z, x.w };
            unsigned short hi[4], lo[4];
#pragma unroll
            for (int i = 0; i < 4; ++i) {
                hi[i] = f2bf(xs[i]);
                lo[i] = f2bf(xs[i] - bf2f(hi[i]));
            }
            *(u16x4*)(khi + base) = *(u16x4*)hi;
            *(u16x4*)(klo + base) = *(u16x4*)lo;
        }
        return;
    }
    int e2 = blockIdx.x - PREP_BLOCKS;          // 0..107
    const float* src = (e2 < 36) ? Wp : (e2 < 72 ? Wv : Wk);
    float* dst = (e2 < 36) ? wpT : (e2 < 72 ? wvT : wkT);
    int tile = e2 % 36;
    int r0 = (tile / 6) * 64, c0 = (tile % 6) * 64;
    if (t < 256) {
#pragma unroll
        for (int rep = 0; rep < 16; ++rep) {
            int idx = rep * 256 + t;
            int r = idx >> 6, c = idx & 63;
            trt[r][c] = src[(size_t)(r0 + r) * C_ + c0 + c];
        }
    }
    __syncthreads();
    if (t < 256) {
#pragma unroll
        for (int rep = 0; rep < 16; ++rep) {
            int idx = rep * 256 + t;
            int rT = idx >> 6, cT = idx & 63;
            dst[(size_t)(c0 + rT) * C_ + r0 + cT] = trt[cT][rT];
        }
    }
}

// ---------------------------------------------------------------------------
// K1: qk — ROUND-THIS: phase 2 was the pipeline's last scalar-load loop
// (64 x 4B loads/thread walking a Wk COLUMN at stride 1536B). Now reads
// WkT[t][h*64..h*64+63] = 64 consecutive floats = 16 float4 loads (4x
// fewer instructions, vectorized, L2-resident); qv stays LDS-broadcast.
// d-sum regroups into 4-term chains (~1-ulp qk shift; fixup net is
// self-consistent; reference-near-tie flip expectation ~0.04 tokens —
// same accepted risk class as r5's regroup). Phase 1 unchanged (r10 form).
// Isolated counters this round settle the prep-vs-qk attribution.
// ---------------------------------------------------------------------------
#define QK_BLOCKS   (8 * H_ * B_)   // 768
#define WQS(d, c) sbuf[(d) * 49 + (c)]

__global__ __launch_bounds__(384) void qk_kernel(const float* __restrict__ query,
                                                 const float* __restrict__ Wq,
                                                 const float* __restrict__ wkT,
                                                 float* __restrict__ qk,
                                                 unsigned short* __restrict__ qkhi,
                                                 unsigned short* __restrict__ qklo) {
    __shared__ float qstage[8][C_];
    __shared__ float qv[8][DH_];
    __shared__ float sbuf[64 * 49];
    int t = threadIdx.x;
    int e = blockIdx.x;
    int ng = e & 7;
    int h = (e >> 3) % H_;
    int b = e / (8 * H_);
    int n0 = ng * 8;
#pragma unroll
    for (int i = 0; i < 8; ++i)
        qstage[i][t] = query[((size_t)(b * N_ + n0 + i)) * C_ + t];
    {
        int i0 = (t < 256) ? (t >> 6) : 0;
        int d = t & 63;
        float accA = 0.f, accB = 0.f;
        for (int c0 = 0; c0 < C_; c0 += 48) {
            __syncthreads();
#pragma unroll
            for (int rep = 0; rep < 8; ++rep) {
                int idx2 = rep * 384 + t;
                int r = idx2 / 48, c = idx2 % 48;
                WQS(r, c) = Wq[(size_t)(h * DH_ + r) * C_ + c0 + c];
            }
            __syncthreads();
            if (t < 256) {
#pragma unroll
                for (int cc = 0; cc < 48; cc += 4) {
                    accA += qstage[i0][c0 + cc + 0] * WQS(d, cc + 0)
                          + qstage[i0][c0 + cc + 1] * WQS(d, cc + 1)
                          + qstage[i0][c0 + cc + 2] * WQS(d, cc + 2)
                          + qstage[i0][c0 + cc + 3] * WQS(d, cc + 3);
                    accB += qstage[i0 + 4][c0 + cc + 0] * WQS(d, cc + 0)
                          + qstage[i0 + 4][c0 + cc + 1] * WQS(d, cc + 1)
                          + qstage[i0 + 4][c0 + cc + 2] * WQS(d, cc + 2)
                          + qstage[i0 + 4][c0 + cc + 3] * WQS(d, cc + 3);
                }
            }
        }
        if (t < 256) {
            qv[i0][d] = accA * SCALE_;
            qv[i0 + 4][d] = accB * SCALE_;
        }
    }
    __syncthreads();
    // phase 2: qk[n,t] = sum_d qv[n][d] * WkT[t][h*64+d] — vectorized row read
    float a[8];
#pragma unroll
    for (int i = 0; i < 8; ++i) a[i] = 0.f;
    {
        const float4* w4 = (const float4*)(wkT + (size_t)t * C_ + h * DH_);
#pragma unroll
        for (int d4 = 0; d4 < DH_ / 4; ++d4) {
            float4 wv4 = w4[d4];
            int d0 = d4 * 4;
#pragma unroll
            for (int i = 0; i < 8; ++i)
                a[i] += qv[i][d0 + 0] * wv4.x + qv[i][d0 + 1] * wv4.y
                      + qv[i][d0 + 2] * wv4.z + qv[i][d0 + 3] * wv4.w;
        }
    }
#pragma unroll
    for (int i = 0; i < 8; ++i) qstage[i][t] = a[i];
    __syncthreads();
    {
        int r = t / 48, c0 = (t % 48) * 8;
        float v[8];
#pragma unroll
        for (int j = 0; j < 8; ++j) v[j] = qstage[r][c0 + j];
        unsigned short hi[8], lo[8];
#pragma unroll
        for (int j = 0; j < 8; ++j) {
            hi[j] = f2bf(v[j]);
            lo[j] = f2bf(v[j] - bf2f(hi[j]));
        }
        size_t o = ((size_t)(b * H_ + h) * N_ + n0 + r) * C_ + c0;
        float4 f0 = { v[0], v[1], v[2], v[3] };
        float4 f1 = { v[4], v[5], v[6], v[7] };
        *(float4*)(qk + o) = f0;
        *(float4*)(qk + o + 4) = f1;
        *(bf16x8*)(qkhi + o) = *(bf16x8*)hi;
        *(bf16x8*)(qklo + o) = *(bf16x8*)lo;
    }
}

// ---------------------------------------------------------------------------
// K2: attn — r14 double-buffered 128-tile (confirmed win; dropped out of
// top-5). STAGE(next) before frag-reads+MFMA; counted wait + raw barrier.
// ---------------------------------------------------------------------------
__global__ __launch_bounds__(256) void attn_kernel(const unsigned short* __restrict__ qkhi,
                                                   const unsigned short* __restrict__ qklo,
                                                   const unsigned short* __restrict__ khi,
                                                   const unsigned short* __restrict__ klo,
                                                   unsigned int* __restrict__ idx,
                                                   unsigned int* __restrict__ flag_cnt,
                                                   unsigned int* __restrict__ flag_list) {
    __shared__ __align__(16) unsigned short sAhi[2][64 * 32];
    __shared__ __align__(16) unsigned short sAlo[2][64 * 32];
    __shared__ __align__(16) unsigned short sBhi[2][128 * 32];
    __shared__ __align__(16) unsigned short sBlo[2][128 * 32];
    int tid = threadIdx.x;
    int w = tid >> 6, l = tid & 63;
    int wm = w >> 1, wn = w & 1;
    int q4 = l >> 4, lm = l & 15;
    int s0 = blockIdx.x * 128;
    int h = blockIdx.y, b = blockIdx.z;
    size_t kbK = ((size_t)b * S_ + s0) * C_;
    size_t kbA = (size_t)(b * H_ + h) * N_ * C_;
    int trow16 = l >> 2;
    int tquart = ((l & 3) ^ ((l >> 3) & 3)) * 8;
    int sw = (q4 ^ ((lm >> 1) & 3)) * 8;

    f32x4 acc[2][4];
#pragma unroll
    for (int tm = 0; tm < 2; ++tm)
#pragma unroll
        for (int nt = 0; nt < 4; ++nt) acc[tm][nt] = (f32x4)0.f;

#define STAGE(buf, kc)                                                                   \
    do {                                                                                 \
        _Pragma("unroll")                                                                \
        for (int i_ = 0; i_ < 6; ++i_) {                                                 \
            int gid = w * 6 + i_;                                                        \
            if (gid < 8) {                                                               \
                gl_lds16(khi + kbK + (size_t)(gid * 16 + trow16) * C_ + (kc) + tquart,   \
                         (char*)sBhi[buf] + gid * 1024);                                 \
            } else if (gid < 16) {                                                       \
                int g2 = gid - 8;                                                        \
                gl_lds16(klo + kbK + (size_t)(g2 * 16 + trow16) * C_ + (kc) + tquart,    \
                         (char*)sBlo[buf] + g2 * 1024);                                  \
            } else if (gid < 20) {                                                       \
                int g2 = gid - 16;                                                       \
                gl_lds16(qkhi + kbA + (size_t)(g2 * 16 + trow16) * C_ + (kc) + tquart,   \
                         (char*)sAhi[buf] + g2 * 1024);                                  \
            } else {                                                                     \
                int g2 = gid - 20;                                                       \
                gl_lds16(qklo + kbA + (size_t)(g2 * 16 + trow16) * C_ + (kc) + tquart,   \
                         (char*)sAlo[buf] + g2 * 1024);                                  \
            }                                                                            \
        }                                                                                \
    } while (0)

    STAGE(0, 0);
    asm volatile("s_waitcnt vmcnt(0)" ::: "memory");
    __builtin_amdgcn_s_barrier();

    for (int t = 0; t < C_ / 32; ++t) {
        int cur = t & 1;
        if (t + 1 < C_ / 32) STAGE(cur ^ 1, (t + 1) * 32);

        bf16x8 ah[2], al[2];
#pragma unroll
        for (int tm = 0; tm < 2; ++tm) {
            int ar = (wm * 32 + tm * 16 + lm) * 32 + sw;
            ah[tm] = *(const bf16x8*)&sAhi[cur][ar];
            al[tm] = *(const bf16x8*)&sAlo[cur][ar];
        }
#pragma unroll
        for (int nt = 0; nt < 4; ++nt) {
            int nr = ((wn * 4 + nt) * 16 + lm) * 32 + sw;
            bf16x8 bh = *(const bf16x8*)&sBhi[cur][nr];
            bf16x8 bl = *(const bf16x8*)&sBlo[cur][nr];
#pragma unroll
            for (int tm = 0; tm < 2; ++tm) {
                acc[tm][nt] = __builtin_amdgcn_mfma_f32_16x16x32_bf16(ah[tm], bh, acc[tm][nt], 0, 0, 0);
                acc[tm][nt] = __builtin_amdgcn_mfma_f32_16x16x32_bf16(ah[tm], bl, acc[tm][nt], 0, 0, 0);
                acc[tm][nt] = __builtin_amdgcn_mfma_f32_16x16x32_bf16(al[tm], bh, acc[tm][nt], 0, 0, 0);
            }
        }
        asm volatile("s_waitcnt vmcnt(0) lgkmcnt(0)" ::: "memory");
        __builtin_amdgcn_sched_barrier(0);
        __builtin_amdgcn_s_barrier();
    }
#undef STAGE
    __syncthreads();

    float* rm1 = (float*)sBhi;
    float* rm2 = rm1 + 256;
    int* ri1 = (int*)(rm2 + 256);
    int* ri2 = ri1 + 256;

#pragma unroll
    for (int nt = 0; nt < 4; ++nt) {
        float m1 = -3.4e38f, m2 = -3.4e38f; int i1 = 0, i2 = 0;
#pragma unroll
        for (int tm = 0; tm < 2; ++tm)
#pragma unroll
            for (int r = 0; r < 4; ++r) {
                float v = acc[tm][nt][r];
                int row = wm * 32 + tm * 16 + q4 * 4 + r;
                if (v > m1) { m2 = m1; i2 = i1; m1 = v; i1 = row; }
                else if (v > m2) { m2 = v; i2 = row; }
            }
#pragma unroll
        for (int off = 16; off < 64; off <<= 1) {
            float om1 = __shfl_xor(m1, off), om2 = __shfl_xor(m2, off);
            int oi1 = __shfl_xor(i1, off), oi2 = __shfl_xor(i2, off);
            bool take = (om1 > m1) || (om1 == m1 && oi1 < i1);
            float w1 = take ? om1 : m1; int wi1 = take ? oi1 : i1;
            float l1 = take ? m1 : om1; int li1 = take ? i1 : oi1;
            float s2 = m2; int si2 = i2;
            if (om2 > s2) { s2 = om2; si2 = oi2; }
            if (l1 > s2) { s2 = l1; si2 = li1; }
            m1 = w1; i1 = wi1; m2 = s2; i2 = si2;
        }
        if (q4 == 0) {
            int cw = (wn * 4 + nt) * 16 + lm;
            rm1[wm * 128 + cw] = m1; rm2[wm * 128 + cw] = m2;
            ri1[wm * 128 + cw] = i1; ri2[wm * 128 + cw] = i2;
        }
    }
    __syncthreads();
    if (tid < 128) {
        float a1 = rm1[tid], a2 = rm2[tid];
        int ai1 = ri1[tid], ai2 = ri2[tid];
        float b1 = rm1[128 + tid], b2 = rm2[128 + tid];
        int bi1 = ri1[128 + tid], bi2 = ri2[128 + tid];
        float w1, s2; int wi1, wi2;
        if (b1 > a1) { w1 = b1; wi1 = bi1; s2 = a1; wi2 = ai1; if (b2 > s2) { s2 = b2; wi2 = bi2; } }
        else         { w1 = a1; wi1 = ai1; s2 = a2; wi2 = ai2; if (b1 > s2) { s2 = b1; wi2 = bi1; } }
        idx[(size_t)(b * H_ + h) * S_ + s0 + tid] = (unsigned)wi1;
        if (w1 - s2 < TAU_) {
            unsigned p = atomicAdd(flag_cnt, 1u);
            if (p < LISTCAP) {
                unsigned tok = (unsigned)((b * H_ + h) * S_ + s0 + tid);
                flag_list[p] = tok | ((unsigned)wi1 << 19) | ((unsigned)wi2 << 25);
            }
        }
    }
}

// ---------------------------------------------------------------------------
// K3: fixup — exact fp32 recompute of two candidate rows for near-ties
// ---------------------------------------------------------------------------
__global__ __launch_bounds__(256) void fixup_kernel(const float* __restrict__ qk,
                                                    const float* __restrict__ key,
                                                    const unsigned int* __restrict__ flag_list,
                                                    const unsigned int* __restrict__ flag_cnt,
                                                    unsigned int* __restrict__ idx) {
    int w = threadIdx.x >> 6, l = threadIdx.x & 63;
    unsigned total = flag_cnt[0];
    if (total > LISTCAP) total = LISTCAP;
    for (unsigned t = blockIdx.x * 4 + w; t < total; t += gridDim.x * 4) {
        unsigned e = flag_list[t];
        unsigned tok = e & 0x7FFFFu;
        int i1 = (int)((e >> 19) & 63u), i2 = (int)((e >> 25) & 63u);
        unsigned bh = tok >> 12;
        unsigned s = tok & 4095u;
        unsigned bb = bh / H_;
        int l32 = l & 31;
        const float* qrow = qk + ((size_t)bh * N_ + (l < 32 ? i1 : i2)) * C_ + l32 * 12;
        const float* krow = key + ((size_t)bb * S_ + s) * C_ + l32 * 12;
        float sum = 0.f;
#pragma unroll
        for (int c = 0; c < 12; ++c) sum += qrow[c] * krow[c];
#pragma unroll
        for (int off = 1; off < 32; off <<= 1) sum += __shfl_xor(sum, off);
        float d1 = __shfl(sum, 0);
        float d2 = __shfl(sum, 32);
        int win = (d2 > d1 || (d2 == d1 && i2 < i1)) ? i2 : i1;
        if (l == 0) idx[(size_t)bh * S_ + s] = (unsigned)win;
    }
}

// ---------------------------------------------------------------------------
// K4: hist_build — 256 threads (r10 form, known-good)
// ---------------------------------------------------------------------------
__global__ __launch_bounds__(256) void hist_build_kernel(const unsigned int* __restrict__ idx,
                                                         unsigned int* __restrict__ offs,
                                                         unsigned int* __restrict__ order) {
    __shared__ unsigned int cnts[N_];
    __shared__ unsigned int pos[N_];
    int tid = threadIdx.x;
    int bh = blockIdx.x;
    if (tid < N_) cnts[tid] = 0u;
    __syncthreads();
    const unsigned int* idxp = idx + (size_t)bh * S_;
    for (int s = tid; s < S_; s += 256) atomicAdd(&cnts[idxp[s]], 1u);
    __syncthreads();
    if (tid < N_) {
        unsigned v = cnts[tid];
        unsigned x = v;
#pragma unroll
        for (int off = 1; off < 64; off <<= 1) {
            unsigned y = __shfl_up(x, off);
            if (tid >= off) x += y;
        }
        unsigned excl = x - v;
        pos[tid] = excl;
        offs[(size_t)bh * 65 + tid] = excl;
        if (tid == 63) offs[(size_t)bh * 65 + 64] = x;   // == S_
    }
    __syncthreads();
    unsigned int* op = order + (size_t)bh * S_;
    for (int s = tid; s < S_; s += 256) {
        unsigned g = idxp[s];
        unsigned p = atomicAdd(&pos[g], 1u);
        op[p] = (unsigned)s;
    }
}

// ---------------------------------------------------------------------------
// K5+K6 fused: aggv — 8-part skew-proof gather on khi (r10 form) +
// coalesced WvT wave-split phase B. Known-good.
// ---------------------------------------------------------------------------
#define AGG_PARTS 8
__global__ __launch_bounds__(512) void aggv_kernel(const unsigned short* __restrict__ khi,
                                                   const unsigned int* __restrict__ order,
                                                   const unsigned int* __restrict__ offs,
                                                   const float* __restrict__ wvT,
                                                   float* __restrict__ gvn) {
    __shared__ float lrows[AGG_PARTS][C_];
    __shared__ float zrow[C_];
    __shared__ float pacc[AGG_PARTS][DH_];
    int tid = threadIdx.x;
    int part = tid >> 6, l = tid & 63;
    int h = blockIdx.y, b = blockIdx.z;
    int bh = b * H_ + h;
    int g = blockIdx.x;
    unsigned beg = offs[(size_t)bh * 65 + g];
    unsigned end = offs[(size_t)bh * 65 + g + 1];
    int cnt = (int)(end - beg);
    float inv = 1.f / ((float)cnt + 1.f);
    const unsigned int* op = order + (size_t)bh * S_ + beg;
    const unsigned int* kbase = (const unsigned int*)(khi + (size_t)b * S_ * C_);
    float a0 = 0.f, a1 = 0.f, a2 = 0.f, a3 = 0.f, a4 = 0.f, a5 = 0.f;
    for (int base = part * 64; base < cnt; base += 64 * AGG_PARTS) {
        int m = cnt - base; if (m > 64) m = 64;
        unsigned sv = (l < m) ? op[base + l] : 0u;
        int i = 0;
        for (; i + 8 <= m; i += 8) {
            int ss[8];
#pragma unroll
            for (int j = 0; j < 8; ++j) ss[j] = __shfl((int)sv, i + j);
            unsigned u[8][3];
#pragma unroll
            for (int j = 0; j < 8; ++j) {
                const unsigned int* kp = kbase + (size_t)ss[j] * (C_ / 2) + l * 3;
                u[j][0] = kp[0]; u[j][1] = kp[1]; u[j][2] = kp[2];
            }
#pragma unroll
            for (int j = 0; j < 8; ++j) {
                a0 += bfu_lo(u[j][0]); a1 += bfu_hi(u[j][0]);
                a2 += bfu_lo(u[j][1]); a3 += bfu_hi(u[j][1]);
                a4 += bfu_lo(u[j][2]); a5 += bfu_hi(u[j][2]);
            }
        }
        for (; i < m; ++i) {
            int s = (int)__shfl((int)sv, i);
            const unsigned int* kp = kbase + (size_t)s * (C_ / 2) + l * 3;
            unsigned u0 = kp[0], u1 = kp[1], u2 = kp[2];
            a0 += bfu_lo(u0); a1 += bfu_hi(u0);
            a2 += bfu_lo(u1); a3 += bfu_hi(u1);
            a4 += bfu_lo(u2); a5 += bfu_hi(u2);
        }
    }
    float* lp = &lrows[part][l * 6];
    lp[0] = a0 * inv; lp[1] = a1 * inv; lp[2] = a2 * inv;
    lp[3] = a3 * inv; lp[4] = a4 * inv; lp[5] = a5 * inv;
    __syncthreads();
    if (tid < C_) {
        float z = lrows[0][tid];
#pragma unroll
        for (int p = 1; p < AGG_PARTS; ++p) z += lrows[p][tid];
        zrow[tid] = z;
    }
    __syncthreads();
    {
        float a = 0.f;
        int cb = part * (C_ / AGG_PARTS);
#pragma unroll 8
        for (int cc = 0; cc < C_ / AGG_PARTS; ++cc) {
            int c = cb + cc;
            a += zrow[c] * wvT[(size_t)c * C_ + h * DH_ + l];
        }
        pacc[part][l] = a;
    }
    __syncthreads();
    if (part == 0) {
        float acc = pacc[0][l];
#pragma unroll
        for (int p = 1; p < AGG_PARTS; ++p) acc += pacc[p][l];
        gvn[((size_t)bh * N_ + g) * DH_ + l] = acc;
    }
}

// ---------------------------------------------------------------------------
// K7: out — 1024 blocks, WpT coalesced (known-good)
// ---------------------------------------------------------------------------
__global__ __launch_bounds__(384) void out_kernel(const float* __restrict__ gvn,
                                                  const float* __restrict__ wpT,
                                                  const float* __restrict__ bp,
                                                  float* __restrict__ out) {
    __shared__ float vals[C_];
    int bn = blockIdx.x;                  // 0..1023
    int b = bn >> 6, n = bn & 63;
    int t = threadIdx.x;
    int h = t >> 6, d = t & 63;
    vals[t] = gvn[((size_t)(b * H_ + h) * N_ + n) * DH_ + d];
    __syncthreads();
    float s = bp[t];
#pragma unroll 8
    for (int c = 0; c < C_; ++c)
        s += vals[c] * wpT[(size_t)c * C_ + t];
    out[(size_t)bn * C_ + t] = s;
}

// ---------------------------------------------------------------------------
extern "C" void kernel_launch(void* const* d_in, const int* in_sizes, int n_in,
                              void* d_out, int out_size, void* d_ws, size_t ws_size,
                              hipStream_t stream) {
    (void)in_sizes; (void)n_in; (void)out_size; (void)ws_size;
    const float* query = (const float*)d_in[0];
    const float* key   = (const float*)d_in[1];
    const float* Wq    = (const float*)d_in[2];
    const float* Wk    = (const float*)d_in[3];
    const float* Wv    = (const float*)d_in[4];
    const float* Wp    = (const float*)d_in[5];
    const float* bp    = (const float*)d_in[6];
    float* out = (float*)d_out;

    char* ws = (char*)d_ws;
    size_t off = 0;
    unsigned short* khi  = (unsigned short*)(ws + off); off += (size_t)B_ * S_ * C_ * 2;
    unsigned short* klo  = (unsigned short*)(ws + off); off += (size_t)B_ * S_ * C_ * 2;
    float* qk            = (float*)(ws + off);          off += (size_t)B_ * H_ * N_ * C_ * 4;
    unsigned short* qkhi = (unsigned short*)(ws + off); off += (size_t)B_ * H_ * N_ * C_ * 2;
    unsigned short* qklo = (unsigned short*)(ws + off); off += (size_t)B_ * H_ * N_ * C_ * 2;
    unsigned int* idx    = (unsigned int*)(ws + off);   off += (size_t)B_ * H_ * S_ * 4;
    unsigned int* order  = (unsigned int*)(ws + off);   off += (size_t)B_ * H_ * S_ * 4;
    unsigned int* offs   = (unsigned int*)(ws + off);   off += (size_t)B_ * H_ * 65 * 4;
    float* gvn           = (float*)(ws + off);          off += (size_t)B_ * H_ * N_ * DH_ * 4;
    float* wpT           = (float*)(ws + off);          off += (size_t)C_ * C_ * 4;
    float* wvT           = (float*)(ws + off);          off += (size_t)C_ * C_ * 4;
    float* wkT           = (float*)(ws + off);          off += (size_t)C_ * C_ * 4;
    unsigned int* fcnt   = (unsigned int*)(ws + off);   off += 256;
    unsigned int* flist  = (unsigned int*)(ws + off);   off += (size_t)LISTCAP * 4;

    hipMemsetAsync(fcnt, 0, 256, stream);

    prep_kernel<<<PREP_BLOCKS + TR_BLOCKS, 384, 0, stream>>>(
        key, khi, klo, Wp, Wv, Wk, wpT, wvT, wkT);
    qk_kernel<<<QK_BLOCKS, 384, 0, stream>>>(query, Wq, wkT, qk, qkhi, qklo);
    attn_kernel<<<dim3(S_ / 128, H_, B_), 256, 0, stream>>>(qkhi, qklo, khi, klo, idx, fcnt, flist);
    fixup_kernel<<<256, 256, 0, stream>>>(qk, key, flist, fcnt, idx);
    hist_build_kernel<<<B_ * H_, 256, 0, stream>>>(idx, offs, order);
    aggv_kernel<<<dim3(N_, H_, B_), 512, 0, stream>>>(khi, order, offs, wvT, gvn);
    out_kernel<<<B_ * N_, 384, 0, stream>>>(gvn, wpT, bp, out);
}